// Round 1
// baseline (200.501 us; speedup 1.0000x reference)
//
#include <hip/hip_runtime.h>
#include <math.h>

#define BB 8
#define NVV 2048
#define NPP 4096
#define DD 64
#define NQ (BB * NVV)     // 16384 vertex rows
#define QT (NQ / 16)      // 1024 query tiles
#define NC1 4             // key chunks KNN1 (64 tiles each)  -- R15: uniform wave length
#define NC2 2             // key chunks KNN2 (64 tiles each)

typedef __attribute__((ext_vector_type(8))) short short8;
typedef __attribute__((ext_vector_type(8))) unsigned short ushort8;
typedef __attribute__((ext_vector_type(4))) float f32x4;

// ws layout (float offsets), audited line-by-line:
// vm      @0        (16384)
// inv_vf_s@16384    (16384)   = 16384/norm
// inv_pf_s@32768    (32768)
// flow    @65536    (65536)
// pc1     @131072   (32*16384 uints = 524288)   -- R15: 4 chunks x 8
// pc2     @655360   (16*16384 uints = 262144)
// vfh     @917504   (QT*1024 ushorts = 524288 floats)
// vfl     @1441792  (+524288)
// pfh     @1966080  (2048 tiles*1024 ushorts = 1048576 floats)
// pfl     @3014656  (+1048576)
// end     @4063232  floats = 15.5 MB

__device__ __forceinline__ unsigned short bf16rn(float x) {
  unsigned u = __float_as_uint(x);
  return (unsigned short)((u + 0x7FFFu + ((u >> 16) & 1u)) >> 16);
}
__device__ __forceinline__ float bf2f(unsigned short h) {
  return __uint_as_float(((unsigned)h) << 16);
}

// Branchless sorted-ascending top-8 insert: 7x v_med3_u32 + 1x max.
__device__ __forceinline__ void net8(unsigned* a, unsigned v) {
#pragma unroll
  for (int k = 0; k < 7; k++) {
    unsigned r;
    asm("v_med3_u32 %0, %1, %2, %3" : "=v"(r) : "v"(v), "v"(a[k]), "v"(a[k + 1]));
    a[k] = r;
  }
  a[7] = a[7] > v ? a[7] : v;
}

__device__ __forceinline__ void ins8(float* tv, int* ti, float v, int id) {
  bool c1 = v > tv[1], c2 = v > tv[2], c3 = v > tv[3];
  bool c4 = v > tv[4], c5 = v > tv[5], c6 = v > tv[6], c7 = v > tv[7];
  tv[0] = c1 ? tv[1] : v;                ti[0] = c1 ? ti[1] : id;
  tv[1] = c2 ? tv[2] : (c1 ? v : tv[1]); ti[1] = c2 ? ti[2] : (c1 ? id : ti[1]);
  tv[2] = c3 ? tv[3] : (c2 ? v : tv[2]); ti[2] = c3 ? ti[3] : (c2 ? id : ti[2]);
  tv[3] = c4 ? tv[4] : (c3 ? v : tv[3]); ti[3] = c4 ? ti[4] : (c3 ? id : ti[3]);
  tv[4] = c5 ? tv[5] : (c4 ? v : tv[4]); ti[4] = c5 ? ti[5] : (c4 ? id : ti[4]);
  tv[5] = c6 ? tv[6] : (c5 ? v : tv[5]); ti[5] = c6 ? ti[6] : (c5 ? id : ti[5]);
  tv[6] = c7 ? tv[7] : (c6 ? v : tv[6]); ti[6] = c7 ? ti[7] : (c6 ? id : ti[6]);
  tv[7] = c7 ? v : tv[7];                ti[7] = c7 ? id : ti[7];
}

// ===== kernel 1: vm (blocks 0..7) + wave-per-tile norm+normalize+staging =====
__global__ __launch_bounds__(256) void k_prep(const float* __restrict__ logits,
                                              const float* __restrict__ vf,
                                              const float* __restrict__ pf,
                                              float* __restrict__ vm,
                                              float* __restrict__ inv_vf_s,
                                              float* __restrict__ inv_pf_s,
                                              unsigned short* __restrict__ vfh,
                                              unsigned short* __restrict__ vfl,
                                              unsigned short* __restrict__ pfh,
                                              unsigned short* __restrict__ pfl,
                                              float* __restrict__ out) {
  int bid = blockIdx.x, t = threadIdx.x;
  if (bid < BB) {
    int b = bid;
    __shared__ float smn[4], smx[4];
    float vals[8];
    float mn = 1e30f, mx = -1e30f;
#pragma unroll
    for (int i = 0; i < 8; i++) {
      float x = logits[b * NVV + t + i * 256];
      float s = 1.0f / (1.0f + expf(-x));
      vals[i] = s;
      mn = fminf(mn, s);
      mx = fmaxf(mx, s);
    }
    for (int o = 32; o; o >>= 1) {
      mn = fminf(mn, __shfl_xor(mn, o, 64));
      mx = fmaxf(mx, __shfl_xor(mx, o, 64));
    }
    int w = t >> 6;
    if ((t & 63) == 0) { smn[w] = mn; smx[w] = mx; }
    __syncthreads();
    mn = fminf(fminf(smn[0], smn[1]), fminf(smn[2], smn[3]));
    mx = fmaxf(fmaxf(smx[0], smx[1]), fmaxf(smx[2], smx[3]));
    float range = mx - mn;
#pragma unroll
    for (int i = 0; i < 8; i++) {
      float v = (vals[i] - mn) / range;
      int g = b * NVV + t + i * 256;
      vm[g] = v;
      out[g * 4 + 3] = v;
    }
  } else {
    int tile_g = (bid - BB) * 4 + (t >> 6);
    int lane = t & 63, c = lane & 15, quad = (lane >> 4) & 3;
    const float* src;
    unsigned short *dh, *dl;
    float* ginv;
    int tile;
    if (tile_g < QT) { tile = tile_g; src = vf; dh = vfh; dl = vfl; ginv = inv_vf_s; }
    else { tile = tile_g - QT; src = pf; dh = pfh; dl = pfl; ginv = inv_pf_s; }
    int row = tile * 16 + c;
    const float* rp = src + (size_t)row * DD + quad * 8;
    float4 a0 = *(const float4*)(rp);
    float4 b0 = *(const float4*)(rp + 4);
    float4 a1 = *(const float4*)(rp + 32);
    float4 b1 = *(const float4*)(rp + 36);
    float xs[16] = {a0.x, a0.y, a0.z, a0.w, b0.x, b0.y, b0.z, b0.w,
                    a1.x, a1.y, a1.z, a1.w, b1.x, b1.y, b1.z, b1.w};
    float ss = 0.f;
#pragma unroll
    for (int j = 0; j < 16; j++) ss = fmaf(xs[j], xs[j], ss);
    ss += __shfl_xor(ss, 16, 64);
    ss += __shfl_xor(ss, 32, 64);
    float inv = 1.0f / fmaxf(sqrtf(ss), 1e-12f);
    if (quad == 0) ginv[row] = 16384.0f * inv;  // pow2 scale: exact ratio later
    ushort8 h, l;
    size_t s0 = (size_t)tile * 128 + lane;
#pragma unroll
    for (int j = 0; j < 8; j++) {
      float xn = xs[j] * inv;
      unsigned short hj = bf16rn(xn);
      h[j] = hj;
      l[j] = bf16rn(xn - bf2f(hj));
    }
    *(ushort8*)(dh + s0 * 8) = h;
    *(ushort8*)(dl + s0 * 8) = l;
#pragma unroll
    for (int j = 0; j < 8; j++) {
      float xn = xs[8 + j] * inv;
      unsigned short hj = bf16rn(xn);
      h[j] = hj;
      l[j] = bf16rn(xn - bf2f(hj));
    }
    *(ushort8*)(dh + (s0 + 64) * 8) = h;
    *(ushort8*)(dl + (s0 + 64) * 8) = l;
  }
}

// ===== kernel 2: MFMA KNN candidate generation (fused KNN1 + KNN2) =====
// R15: uniform 64-tile waves (KNN1 -> 4 chunks, KNN2 stays 2). 6144 waves =
// 6/SIMD, no half-length tail -> VALU issue stays fed. Inner-loop addressing
// hoisted to two incremented pointers; the +1024B second load folds into the
// global_load immediate offset.
__global__ __launch_bounds__(256)
void k_knn(const unsigned short* __restrict__ vfh, const unsigned short* __restrict__ vfl,
           const unsigned short* __restrict__ pfh, const unsigned short* __restrict__ pfl,
           const float* __restrict__ vm,
           unsigned* __restrict__ pc1, unsigned* __restrict__ pc2) {
  int wid = (blockIdx.x * 256 + threadIdx.x) >> 6;
  int lane = threadIdx.x & 63, col = lane & 15, quad = lane >> 4;

  const unsigned short *KH, *KL;
  const float* mask;
  unsigned* PC;
  int qt_g, bt0, row0, ckb;
  if (wid < QT * NC1) {  // KNN1: keys = pf, 4 chunks x 64 tiles
    int ck = wid & 3;
    qt_g = wid >> 2;
    int batch = qt_g >> 7;
    KH = pfh; KL = pfl;
    mask = nullptr;
    bt0 = batch * 256 + ck * 64;
    PC = pc1;
    row0 = ck * 8; ckb = ck * 64;
  } else {               // KNN2: keys = vf, visible only, 2 chunks x 64 tiles
    int w = wid - QT * NC1;
    int ck = w & 1;
    qt_g = w >> 1;
    int batch = qt_g >> 7;
    KH = vfh; KL = vfl;
    mask = vm + batch * NVV;
    bt0 = batch * 128 + ck * 64;
    PC = pc2;
    row0 = ck * 8; ckb = ck * 64;
  }

  size_t ab = (size_t)qt_g * 1024 + lane * 8;
  short8 qh0 = *(const short8*)(vfh + ab);
  short8 qh1 = *(const short8*)(vfh + ab + 512);
  short8 ql0 = *(const short8*)(vfl + ab);
  short8 ql1 = *(const short8*)(vfl + ab + 512);
  // Pin loop-invariant query frags in AGPRs (R14): MFMA reads AGPR A/B
  // operands natively, frees VGPRs for tv + key frags.
  asm volatile("" : "+a"(qh0), "+a"(qh1), "+a"(ql0), "+a"(ql1));

  unsigned tv[8];
#pragma unroll
  for (int k = 0; k < 8; k++) tv[k] = 0u;

  size_t kb = (size_t)bt0 * 1024 + lane * 8;
  const unsigned short* ph = KH + kb;
  const unsigned short* pl = KL + kb;
  const float* mp = mask ? (mask + ckb * 16 + quad * 4) : nullptr;
  int idxq = ckb * 16 + quad * 4;

#pragma unroll 2
  for (int kt = 0; kt < 64; kt++) {
    short8 kh0 = *(const short8*)(ph);
    short8 kh1 = *(const short8*)(ph + 512);
    short8 kl0 = *(const short8*)(pl);
    short8 kl1 = *(const short8*)(pl + 512);
    f32x4 c = {0.f, 0.f, 0.f, 0.f};
    c = __builtin_amdgcn_mfma_f32_16x16x32_bf16(kh0, qh0, c, 0, 0, 0);
    c = __builtin_amdgcn_mfma_f32_16x16x32_bf16(kh1, qh1, c, 0, 0, 0);
    c = __builtin_amdgcn_mfma_f32_16x16x32_bf16(kh0, ql0, c, 0, 0, 0);
    c = __builtin_amdgcn_mfma_f32_16x16x32_bf16(kh1, ql1, c, 0, 0, 0);
    c = __builtin_amdgcn_mfma_f32_16x16x32_bf16(kl0, qh0, c, 0, 0, 0);
    c = __builtin_amdgcn_mfma_f32_16x16x32_bf16(kl1, qh1, c, 0, 0, 0);
    float4 mv;
    if (mask) mv = *(const float4*)(mp);
#pragma unroll
    for (int r = 0; r < 4; r++) {
      unsigned u = (unsigned)fmaxf(fmaf(c[r], 520000.0f, 520000.0f), 0.0f);
      unsigned pk = (u << 12) | (unsigned)(idxq + r);
      if (mask) {
        float mr = (r == 0) ? mv.x : (r == 1) ? mv.y : (r == 2) ? mv.z : mv.w;
        pk = (mr >= 0.5f) ? pk : 0u;
      }
      net8(tv, pk);
    }
    ph += 1024; pl += 1024;
    if (mask) mp += 16;
    idxq += 16;
  }

  // butterfly across the 4 quads (lane bits 4,5)
#pragma unroll
  for (int m = 16; m <= 32; m <<= 1) {
    unsigned ov[8];
#pragma unroll
    for (int k = 0; k < 8; k++) ov[k] = (unsigned)__shfl_xor((int)tv[k], m, 64);
#pragma unroll
    for (int k = 7; k >= 0; k--) net8(tv, ov[k]);
  }

  if (quad == 0) {
    int q = qt_g * 16 + col;
#pragma unroll
    for (int k = 0; k < 8; k++)
      PC[(size_t)(row0 + k) * NQ + q] = tv[k];
  }
}

__device__ __forceinline__ float dot64(const float4* __restrict__ a,
                                       const float4* __restrict__ b) {
  float a0 = 0.f, a1 = 0.f, a2 = 0.f, a3 = 0.f;
#pragma unroll
  for (int c = 0; c < 16; c++) {
    float4 x = a[c], y = b[c];
    a0 = fmaf(x.x, y.x, a0);
    a1 = fmaf(x.y, y.y, a1);
    a2 = fmaf(x.z, y.z, a2);
    a3 = fmaf(x.w, y.w, a3);
  }
  return (a0 + a1) + (a2 + a3);
}

// ===== kernel 3: exact re-rank of 32 KNN1 candidates + flow_init (32 lanes/q) =====
__global__ __launch_bounds__(256) void k_merge_flow(const unsigned* __restrict__ pc,
                                                    const float* __restrict__ vf,
                                                    const float* __restrict__ pf,
                                                    const float* __restrict__ pts,
                                                    const float* __restrict__ vtx,
                                                    const float* __restrict__ inv_pf_s,
                                                    float* __restrict__ flow_ws,
                                                    float* __restrict__ out) {
  int T = blockIdx.x * 256 + threadIdx.x;
  int q = T >> 5, c = T & 31, batch = q >> 11;
  const float4* qp = (const float4*)(vf + (size_t)q * DD);
  float tv[8];
  int ti[8];
#pragma unroll
  for (int k = 0; k < 8; k++) { tv[k] = -3.0e38f; ti[k] = 0; }
  {  // 32 candidate rows / 32 lanes (KNN1 pk always valid)
    unsigned pk = pc[(size_t)c * NQ + q];
    int id = (int)(pk & 0xFFFu);
    int prow = batch * NPP + id;
    float s = dot64(qp, (const float4*)(pf + (size_t)prow * DD)) *
              inv_pf_s[prow] * 6.103515625e-5f;  // * 2^-14 (exact)
    ins8(tv, ti, s, id);
  }
#pragma unroll
  for (int m = 1; m <= 16; m <<= 1) {
    float ov[8];
    int oi[8];
#pragma unroll
    for (int k = 0; k < 8; k++) {
      ov[k] = __shfl_xor(tv[k], m, 64);
      oi[k] = __shfl_xor(ti[k], m, 64);
    }
#pragma unroll
    for (int k = 7; k >= 0; k--)
      if (ov[k] > tv[0]) ins8(tv, ti, ov[k], oi[k]);
  }
  int id = ti[0];
  float sv = tv[0];
#pragma unroll
  for (int k = 1; k < 8; k++) {
    id = (c == k) ? ti[k] : id;
    sv = (c == k) ? tv[k] : sv;
  }

  float ax = 0.f, ay = 0.f, az = 0.f, den = 0.f;
  if (c < 8) {
    int prow = batch * NPP + id;
    float w = sv * 16384.0f / inv_pf_s[prow];  // = raw dot (exact pow2 ratio)
    ax = (pts[prow * 3 + 0] - vtx[q * 3 + 0]) * w;
    ay = (pts[prow * 3 + 1] - vtx[q * 3 + 1]) * w;
    az = (pts[prow * 3 + 2] - vtx[q * 3 + 2]) * w;
    den = w;
  }
#pragma unroll
  for (int m = 1; m <= 16; m <<= 1) {
    ax += __shfl_xor(ax, m, 64);
    ay += __shfl_xor(ay, m, 64);
    az += __shfl_xor(az, m, 64);
    den += __shfl_xor(den, m, 64);
  }
  if (c == 0) {
    float fx = ax / den, fy = ay / den, fz = az / den;
    flow_ws[q * 4 + 0] = fx;
    flow_ws[q * 4 + 1] = fy;
    flow_ws[q * 4 + 2] = fz;
    out[q * 4 + 0] = fx;
    out[q * 4 + 1] = fy;
    out[q * 4 + 2] = fz;
  }
}

// ===== kernel 4: exact re-rank of 16 KNN2 candidates + interpolate invisible =====
__global__ __launch_bounds__(256) void k_merge_final(const unsigned* __restrict__ pc,
                                                     const float* __restrict__ vf,
                                                     const float* __restrict__ vm,
                                                     const float* __restrict__ inv_vf_s,
                                                     const float* __restrict__ flow_ws,
                                                     float* __restrict__ out) {
  int T = blockIdx.x * 256 + threadIdx.x;
  int q = T >> 4, c = T & 15, batch = q >> 11;
  if (vm[q] >= 0.5f) return;
  const float4* qp = (const float4*)(vf + (size_t)q * DD);
  float tv[8];
  int ti[8];
#pragma unroll
  for (int k = 0; k < 8; k++) { tv[k] = -3.0e38f; ti[k] = 0; }
  {  // pk <= 0xFFF = masked sentinel, skip
    unsigned pk = pc[(size_t)c * NQ + q];
    if (pk > 0xFFFu) {
      int id = (int)(pk & 0xFFFu);
      int krow = batch * NVV + id;
      float s = dot64(qp, (const float4*)(vf + (size_t)krow * DD)) *
                inv_vf_s[krow] * 6.103515625e-5f;
      ins8(tv, ti, s, id);
    }
  }
#pragma unroll
  for (int m = 1; m <= 8; m <<= 1) {
    float ov[8];
    int oi[8];
#pragma unroll
    for (int k = 0; k < 8; k++) {
      ov[k] = __shfl_xor(tv[k], m, 64);
      oi[k] = __shfl_xor(ti[k], m, 64);
    }
#pragma unroll
    for (int k = 7; k >= 0; k--)
      if (ov[k] > tv[0]) ins8(tv, ti, ov[k], oi[k]);
  }
  int id = ti[0];
  float sv = tv[0];
#pragma unroll
  for (int k = 1; k < 8; k++) {
    id = (c == k) ? ti[k] : id;
    sv = (c == k) ? tv[k] : sv;
  }

  float ax = 0.f, ay = 0.f, az = 0.f, den = 0.f;
  if (c < 8) {
    int krow = batch * NVV + id;
    float w = sv * 16384.0f / inv_vf_s[krow];
    ax = flow_ws[krow * 4 + 0] * w;
    ay = flow_ws[krow * 4 + 1] * w;
    az = flow_ws[krow * 4 + 2] * w;
    den = w;
  }
#pragma unroll
  for (int m = 1; m <= 8; m <<= 1) {
    ax += __shfl_xor(ax, m, 64);
    ay += __shfl_xor(ay, m, 64);
    az += __shfl_xor(az, m, 64);
    den += __shfl_xor(den, m, 64);
  }
  if (c == 0) {
    out[q * 4 + 0] = ax / den;
    out[q * 4 + 1] = ay / den;
    out[q * 4 + 2] = az / den;
  }
}

extern "C" void kernel_launch(void* const* d_in, const int* in_sizes, int n_in,
                              void* d_out, int out_size, void* d_ws, size_t ws_size,
                              hipStream_t stream) {
  const float* vtx = (const float*)d_in[0];
  const float* pts = (const float*)d_in[1];
  const float* vf = (const float*)d_in[2];
  const float* pf = (const float*)d_in[3];
  const float* lg = (const float*)d_in[4];
  float* out = (float*)d_out;
  float* ws = (float*)d_ws;

  float* vm = ws;
  float* inv_vf_s = ws + 16384;
  float* inv_pf_s = ws + 32768;
  float* flow = ws + 65536;
  unsigned* pc1 = (unsigned*)(ws + 131072);               // 32*16384
  unsigned* pc2 = (unsigned*)(ws + 655360);               // 16*16384
  unsigned short* vfh = (unsigned short*)(ws + 917504);   // 524288 floats
  unsigned short* vfl = (unsigned short*)(ws + 1441792);  // +524288
  unsigned short* pfh = (unsigned short*)(ws + 1966080);  // 1048576
  unsigned short* pfl = (unsigned short*)(ws + 3014656);  // +1048576

  k_prep<<<BB + 768, 256, 0, stream>>>(lg, vf, pf, vm, inv_vf_s, inv_pf_s,
                                       vfh, vfl, pfh, pfl, out);
  k_knn<<<(QT * NC1 + QT * NC2) / 4, 256, 0, stream>>>(vfh, vfl, pfh, pfl,
                                                       vm, pc1, pc2);
  k_merge_flow<<<NQ * 32 / 256, 256, 0, stream>>>(pc1, vf, pf, pts, vtx,
                                                  inv_pf_s, flow, out);
  k_merge_final<<<NQ * 16 / 256, 256, 0, stream>>>(pc2, vf, vm, inv_vf_s, flow, out);
}

// Round 2
// 195.445 us; speedup vs baseline: 1.0259x; 1.0259x over previous
//
#include <hip/hip_runtime.h>
#include <math.h>

#define BB 8
#define NVV 2048
#define NPP 4096
#define DD 64
#define NQ (BB * NVV)     // 16384 vertex rows
#define QT (NQ / 16)      // 1024 query tiles
#define NC1 4             // key chunks KNN1 (64 tiles each)
#define NC2 2             // key chunks KNN2 (64 tiles each)

typedef __attribute__((ext_vector_type(8))) short short8;
typedef __attribute__((ext_vector_type(8))) unsigned short ushort8;
typedef __attribute__((ext_vector_type(4))) float f32x4;

// ws layout (float offsets), audited line-by-line:
// vm      @0        (16384)
// inv_vf_s@16384    (16384)   = 16384/norm
// inv_pf_s@32768    (32768)
// flow    @65536    (65536)
// pc1     @131072   (32*16384 uints = 524288)
// pc2     @655360   (16*16384 uints = 262144)
// vfh     @917504   (QT*1024 ushorts = 524288 floats)
// vfl     @1441792  (+524288)
// pfh     @1966080  (2048 tiles*1024 ushorts = 1048576 floats)
// pfl     @3014656  (+1048576)
// end     @4063232  floats = 15.5 MB

__device__ __forceinline__ unsigned short bf16rn(float x) {
  unsigned u = __float_as_uint(x);
  return (unsigned short)((u + 0x7FFFu + ((u >> 16) & 1u)) >> 16);
}
__device__ __forceinline__ float bf2f(unsigned short h) {
  return __uint_as_float(((unsigned)h) << 16);
}

// Branchless sorted-ascending top-8 insert: 7x v_med3_u32 + 1x max.
__device__ __forceinline__ void net8(unsigned* a, unsigned v) {
#pragma unroll
  for (int k = 0; k < 7; k++) {
    unsigned r;
    asm("v_med3_u32 %0, %1, %2, %3" : "=v"(r) : "v"(v), "v"(a[k]), "v"(a[k + 1]));
    a[k] = r;
  }
  a[7] = a[7] > v ? a[7] : v;
}

__device__ __forceinline__ void ins8(float* tv, int* ti, float v, int id) {
  bool c1 = v > tv[1], c2 = v > tv[2], c3 = v > tv[3];
  bool c4 = v > tv[4], c5 = v > tv[5], c6 = v > tv[6], c7 = v > tv[7];
  tv[0] = c1 ? tv[1] : v;                ti[0] = c1 ? ti[1] : id;
  tv[1] = c2 ? tv[2] : (c1 ? v : tv[1]); ti[1] = c2 ? ti[2] : (c1 ? id : ti[1]);
  tv[2] = c3 ? tv[3] : (c2 ? v : tv[2]); ti[2] = c3 ? ti[3] : (c2 ? id : ti[2]);
  tv[3] = c4 ? tv[4] : (c3 ? v : tv[3]); ti[3] = c4 ? ti[4] : (c3 ? id : ti[3]);
  tv[4] = c5 ? tv[5] : (c4 ? v : tv[4]); ti[4] = c5 ? ti[5] : (c4 ? id : ti[4]);
  tv[5] = c6 ? tv[6] : (c5 ? v : tv[5]); ti[5] = c6 ? ti[6] : (c5 ? id : ti[5]);
  tv[6] = c7 ? tv[7] : (c6 ? v : tv[6]); ti[6] = c7 ? ti[7] : (c6 ? id : ti[6]);
  tv[7] = c7 ? v : tv[7];                ti[7] = c7 ? id : ti[7];
}

// ===== kernel 1: vm (blocks 0..7) + wave-per-tile norm+normalize+staging =====
__global__ __launch_bounds__(256) void k_prep(const float* __restrict__ logits,
                                              const float* __restrict__ vf,
                                              const float* __restrict__ pf,
                                              float* __restrict__ vm,
                                              float* __restrict__ inv_vf_s,
                                              float* __restrict__ inv_pf_s,
                                              unsigned short* __restrict__ vfh,
                                              unsigned short* __restrict__ vfl,
                                              unsigned short* __restrict__ pfh,
                                              unsigned short* __restrict__ pfl,
                                              float* __restrict__ out) {
  int bid = blockIdx.x, t = threadIdx.x;
  if (bid < BB) {
    int b = bid;
    __shared__ float smn[4], smx[4];
    float vals[8];
    float mn = 1e30f, mx = -1e30f;
#pragma unroll
    for (int i = 0; i < 8; i++) {
      float x = logits[b * NVV + t + i * 256];
      float s = 1.0f / (1.0f + expf(-x));
      vals[i] = s;
      mn = fminf(mn, s);
      mx = fmaxf(mx, s);
    }
    for (int o = 32; o; o >>= 1) {
      mn = fminf(mn, __shfl_xor(mn, o, 64));
      mx = fmaxf(mx, __shfl_xor(mx, o, 64));
    }
    int w = t >> 6;
    if ((t & 63) == 0) { smn[w] = mn; smx[w] = mx; }
    __syncthreads();
    mn = fminf(fminf(smn[0], smn[1]), fminf(smn[2], smn[3]));
    mx = fmaxf(fmaxf(smx[0], smx[1]), fmaxf(smx[2], smx[3]));
    float range = mx - mn;
#pragma unroll
    for (int i = 0; i < 8; i++) {
      float v = (vals[i] - mn) / range;
      int g = b * NVV + t + i * 256;
      vm[g] = v;
      out[g * 4 + 3] = v;
    }
  } else {
    int tile_g = (bid - BB) * 4 + (t >> 6);
    int lane = t & 63, c = lane & 15, quad = (lane >> 4) & 3;
    const float* src;
    unsigned short *dh, *dl;
    float* ginv;
    int tile;
    if (tile_g < QT) { tile = tile_g; src = vf; dh = vfh; dl = vfl; ginv = inv_vf_s; }
    else { tile = tile_g - QT; src = pf; dh = pfh; dl = pfl; ginv = inv_pf_s; }
    int row = tile * 16 + c;
    const float* rp = src + (size_t)row * DD + quad * 8;
    float4 a0 = *(const float4*)(rp);
    float4 b0 = *(const float4*)(rp + 4);
    float4 a1 = *(const float4*)(rp + 32);
    float4 b1 = *(const float4*)(rp + 36);
    float xs[16] = {a0.x, a0.y, a0.z, a0.w, b0.x, b0.y, b0.z, b0.w,
                    a1.x, a1.y, a1.z, a1.w, b1.x, b1.y, b1.z, b1.w};
    float ss = 0.f;
#pragma unroll
    for (int j = 0; j < 16; j++) ss = fmaf(xs[j], xs[j], ss);
    ss += __shfl_xor(ss, 16, 64);
    ss += __shfl_xor(ss, 32, 64);
    float inv = 1.0f / fmaxf(sqrtf(ss), 1e-12f);
    if (quad == 0) ginv[row] = 16384.0f * inv;  // pow2 scale: exact ratio later
    ushort8 h, l;
    size_t s0 = (size_t)tile * 128 + lane;
#pragma unroll
    for (int j = 0; j < 8; j++) {
      float xn = xs[j] * inv;
      unsigned short hj = bf16rn(xn);
      h[j] = hj;
      l[j] = bf16rn(xn - bf2f(hj));
    }
    *(ushort8*)(dh + s0 * 8) = h;
    *(ushort8*)(dl + s0 * 8) = l;
#pragma unroll
    for (int j = 0; j < 8; j++) {
      float xn = xs[8 + j] * inv;
      unsigned short hj = bf16rn(xn);
      h[j] = hj;
      l[j] = bf16rn(xn - bf2f(hj));
    }
    *(ushort8*)(dh + (s0 + 64) * 8) = h;
    *(ushort8*)(dl + (s0 + 64) * 8) = l;
  }
}

// ===== kernel 2: MFMA KNN candidate generation (fused KNN1 + KNN2) =====
// R16: k_knn is key-BW-bound (1.61 GB through L2/L3 at ~19 TB/s; R15's extra
// waves did NOT raise VALUBusy). Each wave now serves TWO adjacent query
// tiles against one shared key stream -> key bytes per unit work halve
// (0.79 GB). 8 q-frags pinned in AGPRs (32 AGPRs); two independent
// accumulator chains; pack/net8 per pair unchanged -> pc1/pc2 contents are
// bit-identical to R15 (merge kernels untouched).
__global__ __launch_bounds__(256)
void k_knn(const unsigned short* __restrict__ vfh, const unsigned short* __restrict__ vfl,
           const unsigned short* __restrict__ pfh, const unsigned short* __restrict__ pfl,
           const float* __restrict__ vm,
           unsigned* __restrict__ pc1, unsigned* __restrict__ pc2) {
  int wid = (blockIdx.x * 256 + threadIdx.x) >> 6;
  int lane = threadIdx.x & 63, col = lane & 15, quad = lane >> 4;

  const unsigned short *KH, *KL;
  const float* mask;
  unsigned* PC;
  int pair, bt0, row0, ckb;
  if (wid < (QT / 2) * NC1) {  // KNN1: keys = pf, 4 chunks x 64 tiles
    int ck = wid & 3;
    pair = wid >> 2;           // 0..511, 64 pairs per batch
    int batch = pair >> 6;
    KH = pfh; KL = pfl;
    mask = nullptr;
    bt0 = batch * 256 + ck * 64;
    PC = pc1;
    row0 = ck * 8; ckb = ck * 64;
  } else {                     // KNN2: keys = vf, visible only, 2 chunks x 64 tiles
    int w = wid - (QT / 2) * NC1;
    int ck = w & 1;
    pair = w >> 1;
    int batch = pair >> 6;
    KH = vfh; KL = vfl;
    mask = vm + batch * NVV;
    bt0 = batch * 128 + ck * 64;
    PC = pc2;
    row0 = ck * 8; ckb = ck * 64;
  }
  int qt0 = pair * 2;          // pairs never straddle a batch (128 tiles/batch)

  size_t ab = (size_t)qt0 * 1024 + lane * 8;
  short8 qAh0 = *(const short8*)(vfh + ab);
  short8 qAh1 = *(const short8*)(vfh + ab + 512);
  short8 qAl0 = *(const short8*)(vfl + ab);
  short8 qAl1 = *(const short8*)(vfl + ab + 512);
  short8 qBh0 = *(const short8*)(vfh + ab + 1024);
  short8 qBh1 = *(const short8*)(vfh + ab + 1536);
  short8 qBl0 = *(const short8*)(vfl + ab + 1024);
  short8 qBl1 = *(const short8*)(vfl + ab + 1536);
  // Pin loop-invariant query frags in AGPRs (R14): MFMA reads AGPR A/B
  // operands natively, frees VGPRs for tv + key frags.
  asm volatile("" : "+a"(qAh0), "+a"(qAh1), "+a"(qAl0), "+a"(qAl1),
                    "+a"(qBh0), "+a"(qBh1), "+a"(qBl0), "+a"(qBl1));

  unsigned tvA[8], tvB[8];
#pragma unroll
  for (int k = 0; k < 8; k++) { tvA[k] = 0u; tvB[k] = 0u; }

  size_t kb = (size_t)bt0 * 1024 + lane * 8;
  const unsigned short* ph = KH + kb;
  const unsigned short* pl = KL + kb;
  const float* mp = mask ? (mask + ckb * 16 + quad * 4) : nullptr;
  int idxq = ckb * 16 + quad * 4;

#pragma unroll 2
  for (int kt = 0; kt < 64; kt++) {
    short8 kh0 = *(const short8*)(ph);
    short8 kh1 = *(const short8*)(ph + 512);
    short8 kl0 = *(const short8*)(pl);
    short8 kl1 = *(const short8*)(pl + 512);
    f32x4 cA = {0.f, 0.f, 0.f, 0.f};
    cA = __builtin_amdgcn_mfma_f32_16x16x32_bf16(kh0, qAh0, cA, 0, 0, 0);
    cA = __builtin_amdgcn_mfma_f32_16x16x32_bf16(kh1, qAh1, cA, 0, 0, 0);
    cA = __builtin_amdgcn_mfma_f32_16x16x32_bf16(kh0, qAl0, cA, 0, 0, 0);
    cA = __builtin_amdgcn_mfma_f32_16x16x32_bf16(kh1, qAl1, cA, 0, 0, 0);
    cA = __builtin_amdgcn_mfma_f32_16x16x32_bf16(kl0, qAh0, cA, 0, 0, 0);
    cA = __builtin_amdgcn_mfma_f32_16x16x32_bf16(kl1, qAh1, cA, 0, 0, 0);
    f32x4 cB = {0.f, 0.f, 0.f, 0.f};
    cB = __builtin_amdgcn_mfma_f32_16x16x32_bf16(kh0, qBh0, cB, 0, 0, 0);
    cB = __builtin_amdgcn_mfma_f32_16x16x32_bf16(kh1, qBh1, cB, 0, 0, 0);
    cB = __builtin_amdgcn_mfma_f32_16x16x32_bf16(kh0, qBl0, cB, 0, 0, 0);
    cB = __builtin_amdgcn_mfma_f32_16x16x32_bf16(kh1, qBl1, cB, 0, 0, 0);
    cB = __builtin_amdgcn_mfma_f32_16x16x32_bf16(kl0, qBh0, cB, 0, 0, 0);
    cB = __builtin_amdgcn_mfma_f32_16x16x32_bf16(kl1, qBh1, cB, 0, 0, 0);
    float4 mv;
    if (mask) mv = *(const float4*)(mp);
#pragma unroll
    for (int r = 0; r < 4; r++) {
      float mr;
      if (mask) mr = (r == 0) ? mv.x : (r == 1) ? mv.y : (r == 2) ? mv.z : mv.w;
      unsigned uA = (unsigned)fmaxf(fmaf(cA[r], 520000.0f, 520000.0f), 0.0f);
      unsigned pkA = (uA << 12) | (unsigned)(idxq + r);
      if (mask) pkA = (mr >= 0.5f) ? pkA : 0u;
      net8(tvA, pkA);
      unsigned uB = (unsigned)fmaxf(fmaf(cB[r], 520000.0f, 520000.0f), 0.0f);
      unsigned pkB = (uB << 12) | (unsigned)(idxq + r);
      if (mask) pkB = (mr >= 0.5f) ? pkB : 0u;
      net8(tvB, pkB);
    }
    ph += 1024; pl += 1024;
    if (mask) mp += 16;
    idxq += 16;
  }

  // butterfly across the 4 quads (lane bits 4,5)
#pragma unroll
  for (int m = 16; m <= 32; m <<= 1) {
    unsigned ovA[8], ovB[8];
#pragma unroll
    for (int k = 0; k < 8; k++) {
      ovA[k] = (unsigned)__shfl_xor((int)tvA[k], m, 64);
      ovB[k] = (unsigned)__shfl_xor((int)tvB[k], m, 64);
    }
#pragma unroll
    for (int k = 7; k >= 0; k--) { net8(tvA, ovA[k]); net8(tvB, ovB[k]); }
  }

  if (quad == 0) {
    int qA = qt0 * 16 + col;
#pragma unroll
    for (int k = 0; k < 8; k++) {
      PC[(size_t)(row0 + k) * NQ + qA] = tvA[k];
      PC[(size_t)(row0 + k) * NQ + qA + 16] = tvB[k];
    }
  }
}

__device__ __forceinline__ float dot64(const float4* __restrict__ a,
                                       const float4* __restrict__ b) {
  float a0 = 0.f, a1 = 0.f, a2 = 0.f, a3 = 0.f;
#pragma unroll
  for (int c = 0; c < 16; c++) {
    float4 x = a[c], y = b[c];
    a0 = fmaf(x.x, y.x, a0);
    a1 = fmaf(x.y, y.y, a1);
    a2 = fmaf(x.z, y.z, a2);
    a3 = fmaf(x.w, y.w, a3);
  }
  return (a0 + a1) + (a2 + a3);
}

// ===== kernel 3: exact re-rank of 32 KNN1 candidates + flow_init (32 lanes/q) =====
__global__ __launch_bounds__(256) void k_merge_flow(const unsigned* __restrict__ pc,
                                                    const float* __restrict__ vf,
                                                    const float* __restrict__ pf,
                                                    const float* __restrict__ pts,
                                                    const float* __restrict__ vtx,
                                                    const float* __restrict__ inv_pf_s,
                                                    float* __restrict__ flow_ws,
                                                    float* __restrict__ out) {
  int T = blockIdx.x * 256 + threadIdx.x;
  int q = T >> 5, c = T & 31, batch = q >> 11;
  const float4* qp = (const float4*)(vf + (size_t)q * DD);
  float tv[8];
  int ti[8];
#pragma unroll
  for (int k = 0; k < 8; k++) { tv[k] = -3.0e38f; ti[k] = 0; }
  {  // 32 candidate rows / 32 lanes (KNN1 pk always valid)
    unsigned pk = pc[(size_t)c * NQ + q];
    int id = (int)(pk & 0xFFFu);
    int prow = batch * NPP + id;
    float s = dot64(qp, (const float4*)(pf + (size_t)prow * DD)) *
              inv_pf_s[prow] * 6.103515625e-5f;  // * 2^-14 (exact)
    ins8(tv, ti, s, id);
  }
#pragma unroll
  for (int m = 1; m <= 16; m <<= 1) {
    float ov[8];
    int oi[8];
#pragma unroll
    for (int k = 0; k < 8; k++) {
      ov[k] = __shfl_xor(tv[k], m, 64);
      oi[k] = __shfl_xor(ti[k], m, 64);
    }
#pragma unroll
    for (int k = 7; k >= 0; k--)
      if (ov[k] > tv[0]) ins8(tv, ti, ov[k], oi[k]);
  }
  int id = ti[0];
  float sv = tv[0];
#pragma unroll
  for (int k = 1; k < 8; k++) {
    id = (c == k) ? ti[k] : id;
    sv = (c == k) ? tv[k] : sv;
  }

  float ax = 0.f, ay = 0.f, az = 0.f, den = 0.f;
  if (c < 8) {
    int prow = batch * NPP + id;
    float w = sv * 16384.0f / inv_pf_s[prow];  // = raw dot (exact pow2 ratio)
    ax = (pts[prow * 3 + 0] - vtx[q * 3 + 0]) * w;
    ay = (pts[prow * 3 + 1] - vtx[q * 3 + 1]) * w;
    az = (pts[prow * 3 + 2] - vtx[q * 3 + 2]) * w;
    den = w;
  }
#pragma unroll
  for (int m = 1; m <= 16; m <<= 1) {
    ax += __shfl_xor(ax, m, 64);
    ay += __shfl_xor(ay, m, 64);
    az += __shfl_xor(az, m, 64);
    den += __shfl_xor(den, m, 64);
  }
  if (c == 0) {
    float fx = ax / den, fy = ay / den, fz = az / den;
    flow_ws[q * 4 + 0] = fx;
    flow_ws[q * 4 + 1] = fy;
    flow_ws[q * 4 + 2] = fz;
    out[q * 4 + 0] = fx;
    out[q * 4 + 1] = fy;
    out[q * 4 + 2] = fz;
  }
}

// ===== kernel 4: exact re-rank of 16 KNN2 candidates + interpolate invisible =====
__global__ __launch_bounds__(256) void k_merge_final(const unsigned* __restrict__ pc,
                                                     const float* __restrict__ vf,
                                                     const float* __restrict__ vm,
                                                     const float* __restrict__ inv_vf_s,
                                                     const float* __restrict__ flow_ws,
                                                     float* __restrict__ out) {
  int T = blockIdx.x * 256 + threadIdx.x;
  int q = T >> 4, c = T & 15, batch = q >> 11;
  if (vm[q] >= 0.5f) return;
  const float4* qp = (const float4*)(vf + (size_t)q * DD);
  float tv[8];
  int ti[8];
#pragma unroll
  for (int k = 0; k < 8; k++) { tv[k] = -3.0e38f; ti[k] = 0; }
  {  // pk <= 0xFFF = masked sentinel, skip
    unsigned pk = pc[(size_t)c * NQ + q];
    if (pk > 0xFFFu) {
      int id = (int)(pk & 0xFFFu);
      int krow = batch * NVV + id;
      float s = dot64(qp, (const float4*)(vf + (size_t)krow * DD)) *
                inv_vf_s[krow] * 6.103515625e-5f;
      ins8(tv, ti, s, id);
    }
  }
#pragma unroll
  for (int m = 1; m <= 8; m <<= 1) {
    float ov[8];
    int oi[8];
#pragma unroll
    for (int k = 0; k < 8; k++) {
      ov[k] = __shfl_xor(tv[k], m, 64);
      oi[k] = __shfl_xor(ti[k], m, 64);
    }
#pragma unroll
    for (int k = 7; k >= 0; k--)
      if (ov[k] > tv[0]) ins8(tv, ti, ov[k], oi[k]);
  }
  int id = ti[0];
  float sv = tv[0];
#pragma unroll
  for (int k = 1; k < 8; k++) {
    id = (c == k) ? ti[k] : id;
    sv = (c == k) ? tv[k] : sv;
  }

  float ax = 0.f, ay = 0.f, az = 0.f, den = 0.f;
  if (c < 8) {
    int krow = batch * NVV + id;
    float w = sv * 16384.0f / inv_vf_s[krow];
    ax = flow_ws[krow * 4 + 0] * w;
    ay = flow_ws[krow * 4 + 1] * w;
    az = flow_ws[krow * 4 + 2] * w;
    den = w;
  }
#pragma unroll
  for (int m = 1; m <= 8; m <<= 1) {
    ax += __shfl_xor(ax, m, 64);
    ay += __shfl_xor(ay, m, 64);
    az += __shfl_xor(az, m, 64);
    den += __shfl_xor(den, m, 64);
  }
  if (c == 0) {
    out[q * 4 + 0] = ax / den;
    out[q * 4 + 1] = ay / den;
    out[q * 4 + 2] = az / den;
  }
}

extern "C" void kernel_launch(void* const* d_in, const int* in_sizes, int n_in,
                              void* d_out, int out_size, void* d_ws, size_t ws_size,
                              hipStream_t stream) {
  const float* vtx = (const float*)d_in[0];
  const float* pts = (const float*)d_in[1];
  const float* vf = (const float*)d_in[2];
  const float* pf = (const float*)d_in[3];
  const float* lg = (const float*)d_in[4];
  float* out = (float*)d_out;
  float* ws = (float*)d_ws;

  float* vm = ws;
  float* inv_vf_s = ws + 16384;
  float* inv_pf_s = ws + 32768;
  float* flow = ws + 65536;
  unsigned* pc1 = (unsigned*)(ws + 131072);               // 32*16384
  unsigned* pc2 = (unsigned*)(ws + 655360);               // 16*16384
  unsigned short* vfh = (unsigned short*)(ws + 917504);   // 524288 floats
  unsigned short* vfl = (unsigned short*)(ws + 1441792);  // +524288
  unsigned short* pfh = (unsigned short*)(ws + 1966080);  // 1048576
  unsigned short* pfl = (unsigned short*)(ws + 3014656);  // +1048576

  k_prep<<<BB + 768, 256, 0, stream>>>(lg, vf, pf, vm, inv_vf_s, inv_pf_s,
                                       vfh, vfl, pfh, pfl, out);
  k_knn<<<((QT / 2) * NC1 + (QT / 2) * NC2) / 4, 256, 0, stream>>>(
      vfh, vfl, pfh, pfl, vm, pc1, pc2);
  k_merge_flow<<<NQ * 32 / 256, 256, 0, stream>>>(pc1, vf, pf, pts, vtx,
                                                  inv_pf_s, flow, out);
  k_merge_final<<<NQ * 16 / 256, 256, 0, stream>>>(pc2, vf, vm, inv_vf_s, flow, out);
}

// Round 4
// 174.729 us; speedup vs baseline: 1.1475x; 1.1186x over previous
//
#include <hip/hip_runtime.h>
#include <math.h>

#define BB 8
#define NVV 2048
#define NPP 4096
#define DD 64
#define NQ (BB * NVV)     // 16384 vertex rows
#define QT (NQ / 16)      // 1024 query tiles
#define NC1 2             // key chunks KNN1 (128 tiles each)
#define NC2 2             // key chunks KNN2 (64 tiles each)

typedef __attribute__((ext_vector_type(8))) short short8;
typedef __attribute__((ext_vector_type(8))) unsigned short ushort8;
typedef __attribute__((ext_vector_type(4))) float f32x4;

// ws layout (float offsets), audited line-by-line (R10 lesson):
// vm      @0        (16384)
// inv_vf_s@16384    (16384)   = 16384/norm
// inv_pf_s@32768    (32768)
// flow    @65536    (65536)
// pc1     @131072   (16*16384 uints = 262144)
// pc2     @393216   (16*16384 uints = 262144)
// vfh     @655360   (QT*1024 ushorts = 524288 floats)
// vfl     @1179648  (+524288)
// pfh     @1703936  (2048 tiles*1024 ushorts = 1048576 floats)
// pfl     @2752512  (+1048576)
// end     @3801088  floats = 14.5 MB

__device__ __forceinline__ unsigned short bf16rn(float x) {
  unsigned u = __float_as_uint(x);
  return (unsigned short)((u + 0x7FFFu + ((u >> 16) & 1u)) >> 16);
}
__device__ __forceinline__ float bf2f(unsigned short h) {
  return __uint_as_float(((unsigned)h) << 16);
}

// Branchless sorted-ascending top-8 insert: 7x v_med3_u32 + 1x max.
__device__ __forceinline__ void net8(unsigned* a, unsigned v) {
#pragma unroll
  for (int k = 0; k < 7; k++) {
    unsigned r;
    asm("v_med3_u32 %0, %1, %2, %3" : "=v"(r) : "v"(v), "v"(a[k]), "v"(a[k + 1]));
    a[k] = r;
  }
  a[7] = a[7] > v ? a[7] : v;
}

__device__ __forceinline__ void ins8(float* tv, int* ti, float v, int id) {
  bool c1 = v > tv[1], c2 = v > tv[2], c3 = v > tv[3];
  bool c4 = v > tv[4], c5 = v > tv[5], c6 = v > tv[6], c7 = v > tv[7];
  tv[0] = c1 ? tv[1] : v;                ti[0] = c1 ? ti[1] : id;
  tv[1] = c2 ? tv[2] : (c1 ? v : tv[1]); ti[1] = c2 ? ti[2] : (c1 ? id : ti[1]);
  tv[2] = c3 ? tv[3] : (c2 ? v : tv[2]); ti[2] = c3 ? ti[3] : (c2 ? id : ti[2]);
  tv[3] = c4 ? tv[4] : (c3 ? v : tv[3]); ti[3] = c4 ? ti[4] : (c3 ? id : ti[3]);
  tv[4] = c5 ? tv[5] : (c4 ? v : tv[4]); ti[4] = c5 ? ti[5] : (c4 ? id : ti[4]);
  tv[5] = c6 ? tv[6] : (c5 ? v : tv[5]); ti[5] = c6 ? ti[6] : (c5 ? id : ti[5]);
  tv[6] = c7 ? tv[7] : (c6 ? v : tv[6]); ti[6] = c7 ? ti[7] : (c6 ? id : ti[6]);
  tv[7] = c7 ? v : tv[7];                ti[7] = c7 ? id : ti[7];
}

// ===== kernel 1: vm (blocks 0..7) + wave-per-tile norm+normalize+staging =====
__global__ __launch_bounds__(256) void k_prep(const float* __restrict__ logits,
                                              const float* __restrict__ vf,
                                              const float* __restrict__ pf,
                                              float* __restrict__ vm,
                                              float* __restrict__ inv_vf_s,
                                              float* __restrict__ inv_pf_s,
                                              unsigned short* __restrict__ vfh,
                                              unsigned short* __restrict__ vfl,
                                              unsigned short* __restrict__ pfh,
                                              unsigned short* __restrict__ pfl,
                                              float* __restrict__ out) {
  int bid = blockIdx.x, t = threadIdx.x;
  if (bid < BB) {
    int b = bid;
    __shared__ float smn[4], smx[4];
    float vals[8];
    float mn = 1e30f, mx = -1e30f;
#pragma unroll
    for (int i = 0; i < 8; i++) {
      float x = logits[b * NVV + t + i * 256];
      float s = 1.0f / (1.0f + expf(-x));
      vals[i] = s;
      mn = fminf(mn, s);
      mx = fmaxf(mx, s);
    }
    for (int o = 32; o; o >>= 1) {
      mn = fminf(mn, __shfl_xor(mn, o, 64));
      mx = fmaxf(mx, __shfl_xor(mx, o, 64));
    }
    int w = t >> 6;
    if ((t & 63) == 0) { smn[w] = mn; smx[w] = mx; }
    __syncthreads();
    mn = fminf(fminf(smn[0], smn[1]), fminf(smn[2], smn[3]));
    mx = fmaxf(fmaxf(smx[0], smx[1]), fmaxf(smx[2], smx[3]));
    float range = mx - mn;
#pragma unroll
    for (int i = 0; i < 8; i++) {
      float v = (vals[i] - mn) / range;
      int g = b * NVV + t + i * 256;
      vm[g] = v;
      out[g * 4 + 3] = v;
    }
  } else {
    // 4 tiles per block (one per wave); 3072 tiles total; vf/pf split at
    // tile 1024 (4-aligned -> no block straddles)
    int tile_g = (bid - BB) * 4 + (t >> 6);
    int lane = t & 63, c = lane & 15, quad = (lane >> 4) & 3;
    const float* src;
    unsigned short *dh, *dl;
    float* ginv;
    int tile;
    if (tile_g < QT) { tile = tile_g; src = vf; dh = vfh; dl = vfl; ginv = inv_vf_s; }
    else { tile = tile_g - QT; src = pf; dh = pfh; dl = pfl; ginv = inv_pf_s; }
    int row = tile * 16 + c;
    const float* rp = src + (size_t)row * DD + quad * 8;
    float4 a0 = *(const float4*)(rp);
    float4 b0 = *(const float4*)(rp + 4);
    float4 a1 = *(const float4*)(rp + 32);
    float4 b1 = *(const float4*)(rp + 36);
    float xs[16] = {a0.x, a0.y, a0.z, a0.w, b0.x, b0.y, b0.z, b0.w,
                    a1.x, a1.y, a1.z, a1.w, b1.x, b1.y, b1.z, b1.w};
    float ss = 0.f;
#pragma unroll
    for (int j = 0; j < 16; j++) ss = fmaf(xs[j], xs[j], ss);
    ss += __shfl_xor(ss, 16, 64);
    ss += __shfl_xor(ss, 32, 64);   // all quads now hold the row total
    float inv = 1.0f / fmaxf(sqrtf(ss), 1e-12f);
    if (quad == 0) ginv[row] = 16384.0f * inv;  // pow2 scale: exact ratio later
    ushort8 h, l;
    size_t s0 = (size_t)tile * 128 + lane;      // kk=0 slot
#pragma unroll
    for (int j = 0; j < 8; j++) {
      float xn = xs[j] * inv;
      unsigned short hj = bf16rn(xn);
      h[j] = hj;
      l[j] = bf16rn(xn - bf2f(hj));
    }
    *(ushort8*)(dh + s0 * 8) = h;
    *(ushort8*)(dl + s0 * 8) = l;
#pragma unroll
    for (int j = 0; j < 8; j++) {
      float xn = xs[8 + j] * inv;
      unsigned short hj = bf16rn(xn);
      h[j] = hj;
      l[j] = bf16rn(xn - bf2f(hj));
    }
    *(ushort8*)(dh + (s0 + 64) * 8) = h;      // kk=1 slot
    *(ushort8*)(dl + (s0 + 64) * 8) = l;
  }
}

// ===== kernel 2: MFMA KNN candidate generation (fused KNN1 + KNN2) =====
// R17 (resubmit; prior bench was an infra failure, not a kernel verdict):
// structure reverted verbatim to R0 (fastest k_knn, cheapest merges).
// ONE new variable: XCD-aware block swizzle with batch<->XCD pinning.
// Diagnosis (R15/R16 post-mortems): wall is ~525 cyc per chain-visit per
// SIMD regardless of wave count (3-6/SIMD) or key bytes (0.8-1.6 GB) ->
// latency-bound on L3/IF (~1000-2000 cyc loaded). Cause: 12 MB key set
// round-robin'd over 8 XCDs thrashes every 4 MiB per-XCD L2. Pinning
// batch b to XCD b (bid&7) shrinks per-XCD working set to ~1.5 MB ->
// keys become L2-resident (~200-300 cyc). Work content bit-identical.
__global__ __launch_bounds__(256)
void k_knn(const unsigned short* __restrict__ vfh, const unsigned short* __restrict__ vfl,
           const unsigned short* __restrict__ pfh, const unsigned short* __restrict__ pfl,
           const float* __restrict__ vm,
           unsigned* __restrict__ pc1, unsigned* __restrict__ pc2) {
  // --- XCD swizzle: physical block p -> logical block lb with batch == p&7.
  // KNN1 logical blocks [0,512): batch = lb>>6.  KNN2 [512,1024): batch =
  // (lb-512)>>6.  Bijection: xcd in [0,8), idx in [0,128).
  int p = blockIdx.x;
  int xcd = p & 7, idx = p >> 3;
  int lb = (idx < 64) ? (xcd * 64 + idx) : (512 + xcd * 64 + (idx - 64));
  int wid = lb * 4 + ((int)threadIdx.x >> 6);

  int lane = threadIdx.x & 63, col = lane & 15, quad = lane >> 4;

  const unsigned short *KH, *KL;
  const float* mask;
  unsigned* PC;
  int qt_g, bt0, row0, ckb, ntiles;
  if (wid < QT * NC1) {  // KNN1: keys = pf, 2 chunks x 128 tiles
    int ck = wid & 1;
    qt_g = wid >> 1;
    int batch = qt_g >> 7;
    KH = pfh; KL = pfl;
    mask = nullptr;
    ntiles = 128;
    bt0 = batch * 256 + ck * 128;
    PC = pc1;
    row0 = ck * 8; ckb = ck * 128;
  } else {               // KNN2: keys = vf, visible only, 2 chunks x 64 tiles
    int w = wid - QT * NC1;
    int ck = w & 1;
    qt_g = w >> 1;
    int batch = qt_g >> 7;
    KH = vfh; KL = vfl;
    mask = vm + batch * NVV;
    ntiles = 64;
    bt0 = batch * 128 + ck * 64;
    PC = pc2;
    row0 = ck * 8; ckb = ck * 64;
  }

  size_t ab = (size_t)qt_g * 1024 + lane * 8;
  short8 qh0 = *(const short8*)(vfh + ab);
  short8 qh1 = *(const short8*)(vfh + ab + 512);
  short8 ql0 = *(const short8*)(vfl + ab);
  short8 ql1 = *(const short8*)(vfl + ab + 512);
  // Pin loop-invariant query frags in AGPRs: free homes (MFMA reads AGPR
  // A/B operands directly), frees 16 VGPRs for tv + key frags.
  asm volatile("" : "+a"(qh0), "+a"(qh1), "+a"(ql0), "+a"(ql1));

  unsigned tv[8];
#pragma unroll
  for (int k = 0; k < 8; k++) tv[k] = 0u;

#pragma unroll 2
  for (int kt = 0; kt < ntiles; kt++) {
    size_t bo = (size_t)(bt0 + kt) * 1024 + lane * 8;
    short8 kh0 = *(const short8*)(KH + bo);
    short8 kh1 = *(const short8*)(KH + bo + 512);
    short8 kl0 = *(const short8*)(KL + bo);
    short8 kl1 = *(const short8*)(KL + bo + 512);
    int base16 = (ckb + kt) * 16;
    f32x4 c = {0.f, 0.f, 0.f, 0.f};
    c = __builtin_amdgcn_mfma_f32_16x16x32_bf16(kh0, qh0, c, 0, 0, 0);
    c = __builtin_amdgcn_mfma_f32_16x16x32_bf16(kh1, qh1, c, 0, 0, 0);
    c = __builtin_amdgcn_mfma_f32_16x16x32_bf16(kh0, ql0, c, 0, 0, 0);
    c = __builtin_amdgcn_mfma_f32_16x16x32_bf16(kh1, ql1, c, 0, 0, 0);
    c = __builtin_amdgcn_mfma_f32_16x16x32_bf16(kl0, qh0, c, 0, 0, 0);
    c = __builtin_amdgcn_mfma_f32_16x16x32_bf16(kl1, qh1, c, 0, 0, 0);
    float4 mv;
    if (mask) mv = *(const float4*)(mask + base16 + quad * 4);
#pragma unroll
    for (int r = 0; r < 4; r++) {
      unsigned u = (unsigned)fmaxf(fmaf(c[r], 520000.0f, 520000.0f), 0.0f);
      unsigned pk = (u << 12) | (unsigned)(base16 + quad * 4 + r);
      if (mask) {
        float mr = (r == 0) ? mv.x : (r == 1) ? mv.y : (r == 2) ? mv.z : mv.w;
        pk = (mr >= 0.5f) ? pk : 0u;
      }
      net8(tv, pk);
    }
  }

  // butterfly across the 4 quads (lane bits 4,5)
#pragma unroll
  for (int m = 16; m <= 32; m <<= 1) {
    unsigned ov[8];
#pragma unroll
    for (int k = 0; k < 8; k++) ov[k] = (unsigned)__shfl_xor((int)tv[k], m, 64);
#pragma unroll
    for (int k = 7; k >= 0; k--) net8(tv, ov[k]);
  }

  if (quad == 0) {
    int q = qt_g * 16 + col;
#pragma unroll
    for (int k = 0; k < 8; k++)
      PC[(size_t)(row0 + k) * NQ + q] = tv[k];
  }
}

__device__ __forceinline__ float dot64(const float4* __restrict__ a,
                                       const float4* __restrict__ b) {
  float a0 = 0.f, a1 = 0.f, a2 = 0.f, a3 = 0.f;
#pragma unroll
  for (int c = 0; c < 16; c++) {
    float4 x = a[c], y = b[c];
    a0 = fmaf(x.x, y.x, a0);
    a1 = fmaf(x.y, y.y, a1);
    a2 = fmaf(x.z, y.z, a2);
    a3 = fmaf(x.w, y.w, a3);
  }
  return (a0 + a1) + (a2 + a3);
}

// ===== kernel 3: exact re-rank of 16 KNN1 candidates + flow_init (16 lanes/q) =====
__global__ __launch_bounds__(256) void k_merge_flow(const unsigned* __restrict__ pc,
                                                    const float* __restrict__ vf,
                                                    const float* __restrict__ pf,
                                                    const float* __restrict__ pts,
                                                    const float* __restrict__ vtx,
                                                    const float* __restrict__ inv_pf_s,
                                                    float* __restrict__ flow_ws,
                                                    float* __restrict__ out) {
  int T = blockIdx.x * 256 + threadIdx.x;
  int q = T >> 4, c = T & 15, batch = q >> 11;
  const float4* qp = (const float4*)(vf + (size_t)q * DD);
  float tv[8];
  int ti[8];
#pragma unroll
  for (int k = 0; k < 8; k++) { tv[k] = -3.0e38f; ti[k] = 0; }
  {  // 16 candidate rows / 16 lanes (KNN1 pk always valid)
    unsigned pk = pc[(size_t)c * NQ + q];
    int id = (int)(pk & 0xFFFu);
    int prow = batch * NPP + id;
    float s = dot64(qp, (const float4*)(pf + (size_t)prow * DD)) *
              inv_pf_s[prow] * 6.103515625e-5f;  // * 2^-14 (exact)
    ins8(tv, ti, s, id);
  }
#pragma unroll
  for (int m = 1; m <= 8; m <<= 1) {
    float ov[8];
    int oi[8];
#pragma unroll
    for (int k = 0; k < 8; k++) {
      ov[k] = __shfl_xor(tv[k], m, 64);
      oi[k] = __shfl_xor(ti[k], m, 64);
    }
#pragma unroll
    for (int k = 7; k >= 0; k--)
      if (ov[k] > tv[0]) ins8(tv, ti, ov[k], oi[k]);
  }
  int id = ti[0];
  float sv = tv[0];
#pragma unroll
  for (int k = 1; k < 8; k++) {
    id = (c == k) ? ti[k] : id;
    sv = (c == k) ? tv[k] : sv;
  }

  float ax = 0.f, ay = 0.f, az = 0.f, den = 0.f;
  if (c < 8) {
    int prow = batch * NPP + id;
    float w = sv * 16384.0f / inv_pf_s[prow];  // = raw dot (exact pow2 ratio)
    ax = (pts[prow * 3 + 0] - vtx[q * 3 + 0]) * w;
    ay = (pts[prow * 3 + 1] - vtx[q * 3 + 1]) * w;
    az = (pts[prow * 3 + 2] - vtx[q * 3 + 2]) * w;
    den = w;
  }
#pragma unroll
  for (int m = 1; m <= 8; m <<= 1) {
    ax += __shfl_xor(ax, m, 64);
    ay += __shfl_xor(ay, m, 64);
    az += __shfl_xor(az, m, 64);
    den += __shfl_xor(den, m, 64);
  }
  if (c == 0) {
    float fx = ax / den, fy = ay / den, fz = az / den;
    flow_ws[q * 4 + 0] = fx;
    flow_ws[q * 4 + 1] = fy;
    flow_ws[q * 4 + 2] = fz;
    out[q * 4 + 0] = fx;
    out[q * 4 + 1] = fy;
    out[q * 4 + 2] = fz;
  }
}

// ===== kernel 4: exact re-rank of 16 KNN2 candidates + interpolate invisible =====
__global__ __launch_bounds__(256) void k_merge_final(const unsigned* __restrict__ pc,
                                                     const float* __restrict__ vf,
                                                     const float* __restrict__ vm,
                                                     const float* __restrict__ inv_vf_s,
                                                     const float* __restrict__ flow_ws,
                                                     float* __restrict__ out) {
  int T = blockIdx.x * 256 + threadIdx.x;
  int q = T >> 4, c = T & 15, batch = q >> 11;
  if (vm[q] >= 0.5f) return;
  const float4* qp = (const float4*)(vf + (size_t)q * DD);
  float tv[8];
  int ti[8];
#pragma unroll
  for (int k = 0; k < 8; k++) { tv[k] = -3.0e38f; ti[k] = 0; }
  {  // pk <= 0xFFF = masked sentinel, skip
    unsigned pk = pc[(size_t)c * NQ + q];
    if (pk > 0xFFFu) {
      int id = (int)(pk & 0xFFFu);
      int krow = batch * NVV + id;
      float s = dot64(qp, (const float4*)(vf + (size_t)krow * DD)) *
                inv_vf_s[krow] * 6.103515625e-5f;
      ins8(tv, ti, s, id);
    }
  }
#pragma unroll
  for (int m = 1; m <= 8; m <<= 1) {
    float ov[8];
    int oi[8];
#pragma unroll
    for (int k = 0; k < 8; k++) {
      ov[k] = __shfl_xor(tv[k], m, 64);
      oi[k] = __shfl_xor(ti[k], m, 64);
    }
#pragma unroll
    for (int k = 7; k >= 0; k--)
      if (ov[k] > tv[0]) ins8(tv, ti, ov[k], oi[k]);
  }
  int id = ti[0];
  float sv = tv[0];
#pragma unroll
  for (int k = 1; k < 8; k++) {
    id = (c == k) ? ti[k] : id;
    sv = (c == k) ? tv[k] : sv;
  }

  float ax = 0.f, ay = 0.f, az = 0.f, den = 0.f;
  if (c < 8) {
    int krow = batch * NVV + id;
    float w = sv * 16384.0f / inv_vf_s[krow];
    ax = flow_ws[krow * 4 + 0] * w;
    ay = flow_ws[krow * 4 + 1] * w;
    az = flow_ws[krow * 4 + 2] * w;
    den = w;
  }
#pragma unroll
  for (int m = 1; m <= 8; m <<= 1) {
    ax += __shfl_xor(ax, m, 64);
    ay += __shfl_xor(ay, m, 64);
    az += __shfl_xor(az, m, 64);
    den += __shfl_xor(den, m, 64);
  }
  if (c == 0) {
    out[q * 4 + 0] = ax / den;
    out[q * 4 + 1] = ay / den;
    out[q * 4 + 2] = az / den;
  }
}

extern "C" void kernel_launch(void* const* d_in, const int* in_sizes, int n_in,
                              void* d_out, int out_size, void* d_ws, size_t ws_size,
                              hipStream_t stream) {
  const float* vtx = (const float*)d_in[0];
  const float* pts = (const float*)d_in[1];
  const float* vf = (const float*)d_in[2];
  const float* pf = (const float*)d_in[3];
  const float* lg = (const float*)d_in[4];
  float* out = (float*)d_out;
  float* ws = (float*)d_ws;

  float* vm = ws;
  float* inv_vf_s = ws + 16384;
  float* inv_pf_s = ws + 32768;
  float* flow = ws + 65536;
  unsigned* pc1 = (unsigned*)(ws + 131072);
  unsigned* pc2 = (unsigned*)(ws + 393216);
  unsigned short* vfh = (unsigned short*)(ws + 655360);
  unsigned short* vfl = (unsigned short*)(ws + 1179648);   // +524288 floats
  unsigned short* pfh = (unsigned short*)(ws + 1703936);   // +524288
  unsigned short* pfl = (unsigned short*)(ws + 2752512);   // +1048576

  k_prep<<<BB + 768, 256, 0, stream>>>(lg, vf, pf, vm, inv_vf_s, inv_pf_s,
                                       vfh, vfl, pfh, pfl, out);
  k_knn<<<(QT * NC1 + QT * NC2) / 4, 256, 0, stream>>>(vfh, vfl, pfh, pfl,
                                                       vm, pc1, pc2);
  k_merge_flow<<<NQ * 16 / 256, 256, 0, stream>>>(pc1, vf, pf, pts, vtx,
                                                  inv_pf_s, flow, out);
  k_merge_final<<<NQ * 16 / 256, 256, 0, stream>>>(pc2, vf, vm, inv_vf_s, flow, out);
}